// Round 11
// baseline (353.681 us; speedup 1.0000x reference)
//
#include <hip/hip_runtime.h>
#include <math.h>

#define BATCH 4
#define CH 512
#define NTOK 4096
#define NGRP 32
#define CPG 16
#define GN_EPS 1e-6f

typedef __attribute__((ext_vector_type(8))) short short8;
typedef __attribute__((ext_vector_type(4))) short short4v;
typedef __attribute__((ext_vector_type(4))) float floatx4;

__device__ __forceinline__ short f2bf(float f) {
    unsigned u = __float_as_uint(f);
    u += 0x7fffu + ((u >> 16) & 1u);
    return (short)(u >> 16);
}
__device__ __forceinline__ float bf2f(short s) {
    return __uint_as_float(((unsigned)(unsigned short)s) << 16);
}
// pack 2 floats -> 2 fp8 e4m3 bytes (low 16 bits of result)
__device__ __forceinline__ int pk_fp8(float a, float b) {
    return __builtin_amdgcn_cvt_pk_fp8_f32(a, b, 0, false);
}

__device__ __forceinline__ void load_lds16(const void* g, void* l) {
    __builtin_amdgcn_global_load_lds(
        (const __attribute__((address_space(1))) void*)g,
        (__attribute__((address_space(3))) void*)l,
        16, 0, 0);
}

// ---------------------------------------------------------------------------
// GroupNorm stats, partial: grid (4 parts, 128 bg). partials[bg*4+p]=(sum,ssq)
// ---------------------------------------------------------------------------
__global__ __launch_bounds__(256)
void gn_stats_partial(const float* __restrict__ x, float2* __restrict__ partials)
{
    const int part = blockIdx.x;
    const int bg = blockIdx.y;
    const float4* xp = (const float4*)(x + (size_t)bg * CPG * NTOK) + part * 4096;
    float s = 0.f, ss = 0.f;
    for (int i = threadIdx.x; i < 4096; i += 256) {
        float4 v = xp[i];
        s  += v.x + v.y + v.z + v.w;
        ss += v.x * v.x + v.y * v.y + v.z * v.z + v.w * v.w;
    }
    __shared__ float r0[4], r1[4];
    for (int off = 32; off >= 1; off >>= 1) {
        s  += __shfl_down(s, off);
        ss += __shfl_down(ss, off);
    }
    const int lane = threadIdx.x & 63, wave = threadIdx.x >> 6;
    if (lane == 0) { r0[wave] = s; r1[wave] = ss; }
    __syncthreads();
    if (threadIdx.x == 0) {
        float2 o;
        o.x = r0[0] + r0[1] + r0[2] + r0[3];
        o.y = r1[0] + r1[1] + r1[2] + r1[3];
        partials[bg * 4 + part] = o;
    }
}

// ---------------------------------------------------------------------------
// GroupNorm apply + transpose + bf16. x[b][c][n] -> hnT[b][n][c] bf16.
// ---------------------------------------------------------------------------
__global__ __launch_bounds__(256)
void gn_apply_t(const float* __restrict__ x, const float* __restrict__ gamma,
                const float* __restrict__ beta, const float2* __restrict__ partials,
                short* __restrict__ hnT)
{
    const int b = blockIdx.z;
    const int c0 = blockIdx.y * 32;
    const int n0 = blockIdx.x * 32;
    __shared__ short tile[32][33];
    const int t = threadIdx.x;

    const int cl = t >> 3;
    const int nl = (t & 7) * 4;
    const int c = c0 + cl;
    const int bg = b * NGRP + c / CPG;
    float2 p0 = partials[bg * 4 + 0], p1 = partials[bg * 4 + 1];
    float2 p2 = partials[bg * 4 + 2], p3 = partials[bg * 4 + 3];
    const float inv = 1.f / (float)(CPG * NTOK);
    const float mean = (p0.x + p1.x + p2.x + p3.x) * inv;
    const float var = (p0.y + p1.y + p2.y + p3.y) * inv - mean * mean;
    const float rstd = rsqrtf(var + GN_EPS);
    const float ga = gamma[c] * rstd, be = beta[c] - mean * ga;
    const float4 v = *(const float4*)(x + ((size_t)b * CH + c) * NTOK + n0 + nl);
    tile[cl][nl + 0] = f2bf(v.x * ga + be);
    tile[cl][nl + 1] = f2bf(v.y * ga + be);
    tile[cl][nl + 2] = f2bf(v.z * ga + be);
    tile[cl][nl + 3] = f2bf(v.w * ga + be);
    __syncthreads();

    const int nw = t >> 3;
    const int cw = (t & 7) * 4;
    short4v o;
    o.x = tile[cw + 0][nw];
    o.y = tile[cw + 1][nw];
    o.z = tile[cw + 2][nw];
    o.w = tile[cw + 3][nw];
    *(short4v*)(hnT + ((size_t)b * NTOK + n0 + nw) * CH + c0 + cw) = o;
}

// ---------------------------------------------------------------------------
// Weight casts. Grid (256, 4).
// ---------------------------------------------------------------------------
__global__ __launch_bounds__(256)
void cast_weights(const float* q, const float* k, const float* v, const float* p,
                  short* wqk, short* wv, short* wp)
{
    const float* w; short* o;
    switch (blockIdx.y) {
        case 0: w = q; o = wqk; break;
        case 1: w = k; o = wqk + CH * CH; break;
        case 2: w = v; o = wv; break;
        default: w = p; o = wp; break;
    }
    const int i = blockIdx.x * 256 + threadIdx.x;
    const float4 vv = ((const float4*)w)[i];
    short4v s; s.x = f2bf(vv.x); s.y = f2bf(vv.y); s.z = f2bf(vv.z); s.w = f2bf(vv.w);
    ((short4v*)o)[i] = s;
}

__global__ __launch_bounds__(256)
void concat_bias(const float* q_b, const float* k_b, float* qkb)
{
    const int i = blockIdx.x * 256 + threadIdx.x;
    qkb[i] = (i < CH) ? q_b[i] : k_b[i - CH];
}

__global__ __launch_bounds__(256)
void zero_f32(float* __restrict__ p)
{
    p[blockIdx.x * 256 + threadIdx.x] = 0.f;
}

// ---------------------------------------------------------------------------
// 256x256 4-phase bf16 GEMM (TN), 512 threads, counted-vmcnt pipeline
// + T2 swizzle + T5 setprio.
// MODE 2 = FP8 e4m3 exp(out) + fused fp32 row-sum atomics (scores kernel).
// MODE 1 = bf16 out (unused instantiation path kept for reference).
// ---------------------------------------------------------------------------
#define BAR8() asm volatile("s_barrier" ::: "memory")
#define WAITV4() asm volatile("s_waitcnt vmcnt(4)" ::: "memory")
#define WAITV0() asm volatile("s_waitcnt vmcnt(0)" ::: "memory")
#define LGKMW() asm volatile("s_waitcnt lgkmcnt(0)" ::: "memory")

#define STAGE_A(bufp, kt, u) do {                                             \
    const int r0_ = arow0 + (u) * 64;                                         \
    load_lds16(Ap + (size_t)(m0 + r0_) * lda + (kt) * 64 + sc * 8,            \
               &lds[(bufp) * NSH + r0_ * 64 + lc * 8]);                       \
    load_lds16(Ap + (size_t)(m0 + r0_ + 128) * lda + (kt) * 64 + sc * 8,      \
               &lds[(bufp) * NSH + (r0_ + 128) * 64 + lc * 8]);               \
} while (0)

#define STAGE_B(bufp, kt, u) do {                                             \
    const int r0_ = brow0 + (u) * 32;                                         \
    load_lds16(Bp + (size_t)(n0 + r0_) * ldb + (kt) * 64 + sc * 8,            \
               &lds[(bufp) * NSH + 16384 + r0_ * 64 + lc * 8]);               \
    load_lds16(Bp + (size_t)(n0 + r0_ + 128) * ldb + (kt) * 64 + sc * 8,      \
               &lds[(bufp) * NSH + 16384 + (r0_ + 128) * 64 + lc * 8]);       \
} while (0)

#define READA(bufp, mh) do {                                                  \
    const short* bp_ = &lds[(bufp) * NSH];                                    \
    _Pragma("unroll")                                                         \
    for (int mt = 0; mt < 4; mt++) {                                          \
        const int row_ = wr * 128 + (mh) * 64 + mt * 16 + lr;                 \
        af[mt][0] = *(const short8*)&bp_[row_ * 64 + ((0 + lq) ^ (lr & 7)) * 8]; \
        af[mt][1] = *(const short8*)&bp_[row_ * 64 + ((4 + lq) ^ (lr & 7)) * 8]; \
    } } while (0)

#define READB(bufp, nh) do {                                                  \
    const short* bp_ = &lds[(bufp) * NSH + 16384];                            \
    _Pragma("unroll")                                                         \
    for (int nt = 0; nt < 2; nt++) {                                          \
        const int row_ = wc * 64 + (nh) * 32 + nt * 16 + lr;                  \
        bfr[(nh) * 2 + nt][0] = *(const short8*)&bp_[row_ * 64 + ((0 + lq) ^ (lr & 7)) * 8]; \
        bfr[(nh) * 2 + nt][1] = *(const short8*)&bp_[row_ * 64 + ((4 + lq) ^ (lr & 7)) * 8]; \
    } } while (0)

#define MMAQ(mh, nh) do {                                                     \
    __builtin_amdgcn_s_setprio(1);                                            \
    _Pragma("unroll")                                                         \
    for (int mt = 0; mt < 4; mt++)                                            \
        _Pragma("unroll")                                                     \
        for (int nt = 0; nt < 2; nt++) {                                      \
            acc[(mh)*4+mt][(nh)*2+nt] = __builtin_amdgcn_mfma_f32_16x16x32_bf16( \
                af[mt][0], bfr[(nh)*2+nt][0], acc[(mh)*4+mt][(nh)*2+nt], 0, 0, 0); \
            acc[(mh)*4+mt][(nh)*2+nt] = __builtin_amdgcn_mfma_f32_16x16x32_bf16( \
                af[mt][1], bfr[(nh)*2+nt][1], acc[(mh)*4+mt][(nh)*2+nt], 0, 0, 0); \
        }                                                                     \
    __builtin_amdgcn_s_setprio(0);                                            \
} while (0)

template<int MODE, int SWAP_XY, int SPLITK>
__global__ __launch_bounds__(512)
void gemm8p(const short* __restrict__ A, const short* __restrict__ B,
            void* __restrict__ Cout, float* __restrict__ rs, float scale,
            int K, int lda, int ldb, int ldc, long sA, long sB, long sC)
{
    constexpr int NSH = 32768;                  // shorts per K-tile buffer
    __shared__ __align__(16) short lds[65536];  // 128 KiB

    const int z = blockIdx.z;
    const int zb = SPLITK ? (z & 3) : z;
    const int koff = SPLITK ? (z >> 2) * K : 0;
    const short* Ap = A + (size_t)zb * sA + koff;
    const short* Bp = B + (size_t)zb * sB + koff;
    const int m0 = (SWAP_XY ? blockIdx.x : blockIdx.y) * 256;
    const int n0 = (SWAP_XY ? blockIdx.y : blockIdx.x) * 256;

    const int t = threadIdx.x;
    const int w = t >> 6, lane = t & 63;
    const int wr = w >> 2, wc = w & 3;
    const int lr = lane & 15, lq = lane >> 4;

    const int l8 = lane >> 3;
    const int lc = lane & 7;
    const int sc = lc ^ l8;              // T2 swizzled source chunk
    const int arow0 = w * 8 + l8;
    const int brow0 = (w >> 2) * 64 + (w & 3) * 8 + l8;

    short8 af[4][2], bfr[4][2];
    floatx4 acc[8][4];
#pragma unroll
    for (int i = 0; i < 8; i++)
#pragma unroll
        for (int j = 0; j < 4; j++)
            acc[i][j] = (floatx4){0.f, 0.f, 0.f, 0.f};

    const int NKT = K >> 6;
    const int NIT = K >> 7;

    STAGE_A(0, 0, 0); STAGE_B(0, 0, 0); STAGE_A(0, 0, 1); STAGE_B(0, 0, 1);
    STAGE_A(1, 1, 0); STAGE_B(1, 1, 0);

    for (int it = 0; it < NIT; it++) {
        const int ktb = 2 * it + 1;
        int kt2 = 2 * it + 2; if (kt2 >= NKT) kt2 -= 2;
        int kt3 = 2 * it + 3; if (kt3 >= NKT) kt3 -= 2;
        // P0
        WAITV4(); BAR8();
        READA(0, 0); READB(0, 0); READB(0, 1);
        STAGE_B(1, ktb, 1); STAGE_A(1, ktb, 1);
        BAR8(); LGKMW(); MMAQ(0, 0); MMAQ(0, 1); BAR8();
        // P1
        READA(0, 1);
        STAGE_A(0, kt2, 0); STAGE_B(0, kt2, 0);
        BAR8(); LGKMW(); MMAQ(1, 0); MMAQ(1, 1); BAR8();
        // P2
        WAITV4(); BAR8();
        READA(1, 0); READB(1, 0); READB(1, 1);
        STAGE_A(0, kt2, 1); STAGE_B(0, kt2, 1);
        BAR8(); LGKMW(); MMAQ(0, 0); MMAQ(0, 1); BAR8();
        // P3
        READA(1, 1);
        STAGE_A(1, kt3, 0); STAGE_B(1, kt3, 0);
        BAR8(); LGKMW(); MMAQ(1, 0); MMAQ(1, 1); BAR8();
    }
    WAITV0(); BAR8();      // drain clamped tail stages before LDS reuse

    const size_t cz = (size_t)z * sC;
    if (MODE == 2) {
        // FP8 epilogue: E = exp(v) as e4m3 bytes; RS from fp32 pre-rounding.
        char* Cs8 = (char*)lds;              // 256x256 bytes, chunk-swizzled
        char* Cout8 = (char*)Cout;
#pragma unroll
        for (int mh = 0; mh < 2; mh++)
#pragma unroll
            for (int mt = 0; mt < 4; mt++)
#pragma unroll
                for (int r = 0; r < 4; r++) {
                    const int row = wr * 128 + mh * 64 + mt * 16 + lq * 4 + r;
                    float v[4];
                    float sm = 0.f;
#pragma unroll
                    for (int nh = 0; nh < 2; nh++)
#pragma unroll
                        for (int nt = 0; nt < 2; nt++) {
                            float e = __expf(
                                acc[mh * 4 + mt][nh * 2 + nt][r] * scale);
                            v[nh * 2 + nt] = e;
                            sm += e;
                        }
                    const int rsw = row & 7;
                    const int base = row * 256;
                    const int p01 = pk_fp8(v[0], v[1]);
                    const int p23 = pk_fp8(v[2], v[3]);
                    // chunk = wc*4 + nh*2 + nt; byte pos = (chunk^rsw)*16 + lr
                    Cs8[base + (((wc * 4 + 0) ^ rsw) << 4) + lr] = (char)(p01 & 0xff);
                    Cs8[base + (((wc * 4 + 1) ^ rsw) << 4) + lr] = (char)((p01 >> 8) & 0xff);
                    Cs8[base + (((wc * 4 + 2) ^ rsw) << 4) + lr] = (char)(p23 & 0xff);
                    Cs8[base + (((wc * 4 + 3) ^ rsw) << 4) + lr] = (char)((p23 >> 8) & 0xff);
                    sm += __shfl_xor(sm, 1);
                    sm += __shfl_xor(sm, 2);
                    sm += __shfl_xor(sm, 4);
                    sm += __shfl_xor(sm, 8);
                    if (lr == 0)
                        atomicAdd(&rs[(size_t)zb * NTOK + m0 + row], sm);
                }
        __syncthreads();
#pragma unroll
        for (int i2 = 0; i2 < 8; i2++) {
            const int idx = i2 * 512 + t;          // 4096 16B-chunks
            const int row = idx >> 4;
            const int ch = idx & 15;
            int4 val = *(const int4*)&Cs8[row * 256 + ((ch ^ (row & 7)) << 4)];
            *(int4*)&Cout8[cz + (size_t)(m0 + row) * ldc + n0 + ch * 16] = val;
        }
    } else {
        // bf16 epilogue (row-XOR-swizzled Cs + coalesced 512B stores)
        short* Cs = lds;
        short* CoutS = (short*)Cout;
#pragma unroll
        for (int mh = 0; mh < 2; mh++)
#pragma unroll
            for (int mt = 0; mt < 4; mt++)
#pragma unroll
                for (int r = 0; r < 4; r++) {
                    const int row = wr * 128 + mh * 64 + mt * 16 + lq * 4 + r;
#pragma unroll
                    for (int nh = 0; nh < 2; nh++)
#pragma unroll
                        for (int nt = 0; nt < 2; nt++) {
                            const int col = wc * 64 + nh * 32 + nt * 16 + lr;
                            float v = acc[mh * 4 + mt][nh * 2 + nt][r] * scale;
                            Cs[row * 256 + (col ^ ((row & 7) << 4))] = f2bf(v);
                        }
                }
        __syncthreads();
#pragma unroll
        for (int i2 = 0; i2 < 16; i2++) {
            const int row = w * 32 + i2 * 2 + (lane >> 5);
            const int col = (lane & 31) * 8;
            short8 val = *(const short8*)&Cs[row * 256 + (col ^ ((row & 7) << 4))];
            *(short8*)&CoutS[cz + (size_t)(m0 + row) * ldc + n0 + col] = val;
        }
    }
}

// ---------------------------------------------------------------------------
// 256x256 4-phase FP8 GEMM (TN), 512 threads. BK=128 fp8 elems = 128B rows:
// byte-identical memory geometry (staging, swizzle, vmcnt ledger) to the
// bf16 BK=64 kernel above. A,B fp8 e4m3; MFMA f32_16x16x32_fp8_fp8 (bf16
// rate, half the bytes). Output: bf16 partials (split-K) for proj B_COMBINE.
// ---------------------------------------------------------------------------
#define STAGE_A8(bufp, kt, u) do {                                            \
    const int r0_ = arow0 + (u) * 64;                                         \
    load_lds16(Ap + (size_t)(m0 + r0_) * lda + (kt) * 128 + sc * 16,          \
               &ldsb[(bufp) * NSHB + r0_ * 128 + lc * 16]);                   \
    load_lds16(Ap + (size_t)(m0 + r0_ + 128) * lda + (kt) * 128 + sc * 16,    \
               &ldsb[(bufp) * NSHB + (r0_ + 128) * 128 + lc * 16]);           \
} while (0)

#define STAGE_B8(bufp, kt, u) do {                                            \
    const int r0_ = brow0 + (u) * 32;                                         \
    load_lds16(Bp + (size_t)(n0 + r0_) * ldb + (kt) * 128 + sc * 16,          \
               &ldsb[(bufp) * NSHB + 32768 + r0_ * 128 + lc * 16]);           \
    load_lds16(Bp + (size_t)(n0 + r0_ + 128) * ldb + (kt) * 128 + sc * 16,    \
               &ldsb[(bufp) * NSHB + 32768 + (r0_ + 128) * 128 + lc * 16]);   \
} while (0)

#define READA8(bufp, mh) do {                                                 \
    const char* bp_ = &ldsb[(bufp) * NSHB];                                   \
    _Pragma("unroll")                                                         \
    for (int mt = 0; mt < 4; mt++) {                                          \
        const int row_ = wr * 128 + (mh) * 64 + mt * 16 + lr;                 \
        _Pragma("unroll")                                                     \
        for (int ks = 0; ks < 4; ks++) {                                      \
            const int off = ks * 32 + lq * 8;                                 \
            const int swz = (((off >> 4) ^ (lr & 7)) << 4) | (off & 15);      \
            af8[mt][ks] = *(const long*)&bp_[row_ * 128 + swz];               \
        }                                                                     \
    } } while (0)

#define READB8(bufp, nh) do {                                                 \
    const char* bp_ = &ldsb[(bufp) * NSHB + 32768];                           \
    _Pragma("unroll")                                                         \
    for (int nt = 0; nt < 2; nt++) {                                          \
        const int row_ = wc * 64 + (nh) * 32 + nt * 16 + lr;                  \
        _Pragma("unroll")                                                     \
        for (int ks = 0; ks < 4; ks++) {                                      \
            const int off = ks * 32 + lq * 8;                                 \
            const int swz = (((off >> 4) ^ (lr & 7)) << 4) | (off & 15);      \
            bfr8[(nh) * 2 + nt][ks] = *(const long*)&bp_[row_ * 128 + swz];   \
        }                                                                     \
    } } while (0)

#define MMAQ8(mh, nh) do {                                                    \
    __builtin_amdgcn_s_setprio(1);                                            \
    _Pragma("unroll")                                                         \
    for (int mt = 0; mt < 4; mt++)                                            \
        _Pragma("unroll")                                                     \
        for (int nt = 0; nt < 2; nt++)                                        \
            _Pragma("unroll")                                                 \
            for (int ks = 0; ks < 4; ks++)                                    \
                acc[(mh)*4+mt][(nh)*2+nt] =                                   \
                    __builtin_amdgcn_mfma_f32_16x16x32_fp8_fp8(               \
                        af8[mt][ks], bfr8[(nh)*2+nt][ks],                     \
                        acc[(mh)*4+mt][(nh)*2+nt], 0, 0, 0);                  \
    __builtin_amdgcn_s_setprio(0);                                            \
} while (0)

template<int SWAP_XY, int SPLITK>
__global__ __launch_bounds__(512)
void gemm8p_fp8(const char* __restrict__ A, const char* __restrict__ B,
                short* __restrict__ Cout, float scale,
                int K, int lda, int ldb, int ldc, long sA, long sB, long sC)
{
    constexpr int NSHB = 65536;                 // bytes per K-tile buffer
    __shared__ __align__(16) char ldsb[131072];

    const int z = blockIdx.z;
    const int zb = SPLITK ? (z & 3) : z;
    const int koff = SPLITK ? (z >> 2) * K : 0;
    const char* Ap = A + (size_t)zb * sA + koff;
    const char* Bp = B + (size_t)zb * sB + koff;
    const int m0 = (SWAP_XY ? blockIdx.x : blockIdx.y) * 256;
    const int n0 = (SWAP_XY ? blockIdx.y : blockIdx.x) * 256;

    const int t = threadIdx.x;
    const int w = t >> 6, lane = t & 63;
    const int wr = w >> 2, wc = w & 3;
    const int lr = lane & 15, lq = lane >> 4;

    const int l8 = lane >> 3;
    const int lc = lane & 7;
    const int sc = lc ^ l8;              // T2 swizzled source chunk (16B)
    const int arow0 = w * 8 + l8;
    const int brow0 = (w >> 2) * 64 + (w & 3) * 8 + l8;

    long af8[4][4], bfr8[4][4];
    floatx4 acc[8][4];
#pragma unroll
    for (int i = 0; i < 8; i++)
#pragma unroll
        for (int j = 0; j < 4; j++)
            acc[i][j] = (floatx4){0.f, 0.f, 0.f, 0.f};

    const int NKT = K >> 7;              // 128-elem K-tiles
    const int NIT = K >> 8;

    STAGE_A8(0, 0, 0); STAGE_B8(0, 0, 0); STAGE_A8(0, 0, 1); STAGE_B8(0, 0, 1);
    STAGE_A8(1, 1, 0); STAGE_B8(1, 1, 0);

    for (int it = 0; it < NIT; it++) {
        const int ktb = 2 * it + 1;
        int kt2 = 2 * it + 2; if (kt2 >= NKT) kt2 -= 2;
        int kt3 = 2 * it + 3; if (kt3 >= NKT) kt3 -= 2;
        // P0
        WAITV4(); BAR8();
        READA8(0, 0); READB8(0, 0); READB8(0, 1);
        STAGE_B8(1, ktb, 1); STAGE_A8(1, ktb, 1);
        BAR8(); LGKMW(); MMAQ8(0, 0); MMAQ8(0, 1); BAR8();
        // P1
        READA8(0, 1);
        STAGE_A8(0, kt2, 0); STAGE_B8(0, kt2, 0);
        BAR8(); LGKMW(); MMAQ8(1, 0); MMAQ8(1, 1); BAR8();
        // P2
        WAITV4(); BAR8();
        READA8(1, 0); READB8(1, 0); READB8(1, 1);
        STAGE_A8(0, kt2, 1); STAGE_B8(0, kt2, 1);
        BAR8(); LGKMW(); MMAQ8(0, 0); MMAQ8(0, 1); BAR8();
        // P3
        READA8(1, 1);
        STAGE_A8(1, kt3, 0); STAGE_B8(1, kt3, 0);
        BAR8(); LGKMW(); MMAQ8(1, 0); MMAQ8(1, 1); BAR8();
    }
    WAITV0(); BAR8();

    // bf16 epilogue (partials out), identical to the bf16 kernel's.
    short* Cs = (short*)ldsb;
    const size_t cz = (size_t)z * sC;
#pragma unroll
    for (int mh = 0; mh < 2; mh++)
#pragma unroll
        for (int mt = 0; mt < 4; mt++)
#pragma unroll
            for (int r = 0; r < 4; r++) {
                const int row = wr * 128 + mh * 64 + mt * 16 + lq * 4 + r;
#pragma unroll
                for (int nh = 0; nh < 2; nh++)
#pragma unroll
                    for (int nt = 0; nt < 2; nt++) {
                        const int col = wc * 64 + nh * 32 + nt * 16 + lr;
                        float v = acc[mh * 4 + mt][nh * 2 + nt][r] * scale;
                        Cs[row * 256 + (col ^ ((row & 7) << 4))] = f2bf(v);
                    }
            }
    __syncthreads();
#pragma unroll
    for (int i2 = 0; i2 < 16; i2++) {
        const int row = w * 32 + i2 * 2 + (lane >> 5);
        const int col = (lane & 31) * 8;
        short8 val = *(const short8*)&Cs[row * 256 + (col ^ ((row & 7) << 4))];
        *(short8*)&Cout[cz + (size_t)(m0 + row) * ldc + n0 + col] = val;
    }
}

// ---------------------------------------------------------------------------
// bf16 MFMA GEMM (TN) 128x128 2-barrier. T2 swizzle.
// FP8OUT (MODE 1): epilogue converts to fp8 e4m3 (V conv -> fp8 V).
// B_COMBINE: B operand is (B + B2)/rs[row] built in reg-staging (proj).
// ---------------------------------------------------------------------------
template<int BM, int BN, int BK, int WAVES_M, int MODE, int BIAS_M,
         int BIAS_N, int ADD_RES, int SWAP_XY, int SPLITK, int RSUM,
         int B_COMBINE, int FP8OUT>
__global__ __launch_bounds__(256)
void mfma_gemm(const short* __restrict__ A, const short* __restrict__ B,
               const short* __restrict__ B2, void* __restrict__ Cv,
               const float* __restrict__ bias, const float* __restrict__ res,
               float* __restrict__ rs, float scale,
               int K, int lda, int ldb, int ldc,
               long sA, long sB, long sC)
{
    constexpr int WAVES_N = 4 / WAVES_M;
    constexpr int WM = BM / WAVES_M;
    constexpr int WN = BN / WAVES_N;
    constexpr int MT = WM / 16;
    constexpr int NT = WN / 16;
    constexpr int KS = BK / 32;
    constexpr int TPR = BK / 8;
    constexpr int RPI = 256 / TPR;
    constexpr int CPITCH = BN + 8;
    constexpr int CP8 = BN + 32;
    constexpr int STAGE = BM * BK + BN * BK;
    constexpr int EPI = (MODE >= 1) ? (FP8OUT ? (64 * CP8 + 1) / 2 : 64 * CPITCH) : 0;
    constexpr int LDSE = STAGE > EPI ? STAGE : EPI;

    __shared__ __align__(16) short lds[LDSE];
    short* As = lds;
    short* Bs = lds + BM * BK;

    const int z = blockIdx.z;
    const int zb = SPLITK ? (z & 3) : z;
    const int koff = SPLITK ? (z >> 2) * K : 0;
    const short* Ap = A + (size_t)zb * sA + koff;
    const short* Bp = B + (size_t)zb * sB + koff;
    const short* Bp2 = B_COMBINE ? (B2 + (size_t)zb * sB + koff) : nullptr;

    const int m0 = (SWAP_XY ? blockIdx.x : blockIdx.y) * BM;
    const int n0 = (SWAP_XY ? blockIdx.y : blockIdx.x) * BN;
    const int t = threadIdx.x;
    const int w = t >> 6, lane = t & 63;
    const int wm = (w % WAVES_M) * WM;
    const int wn = (w / WAVES_M) * WN;
    const int lr = lane & 15, lq = lane >> 4;

    floatx4 acc[MT][NT];
#pragma unroll
    for (int mt = 0; mt < MT; mt++)
#pragma unroll
        for (int nt = 0; nt < NT; nt++)
            acc[mt][nt] = (floatx4){0.f, 0.f, 0.f, 0.f};

    const int rA = t / TPR;
    const int kA = (t % TPR) * 8;
    const int kAs = ((t % TPR) ^ (rA & (TPR - 1))) * 8;
    const int xorv = (lr & (TPR - 1)) * 8;

    float binv[B_COMBINE ? BN / RPI : 1];
    if (B_COMBINE) {
#pragma unroll
        for (int r = 0; r < BN / RPI; r++)
            binv[r] = 1.f / rs[(size_t)zb * NTOK + n0 + r * RPI + rA];
    }

    for (int k0 = 0; k0 < K; k0 += BK) {
#pragma unroll
        for (int r = 0; r < BM; r += RPI)
            load_lds16(Ap + (size_t)(m0 + r + rA) * lda + k0 + kAs,
                       &As[(r + rA) * BK + kA]);
        if (B_COMBINE) {
#pragma unroll
            for (int r = 0; r < BN; r += RPI) {
                const size_t off = (size_t)(n0 + r + rA) * ldb + k0 + kAs;
                short8 a8 = *(const short8*)&Bp[off];
                short8 b8 = *(const short8*)&Bp2[off];
                short8 o8;
#pragma unroll
                for (int e = 0; e < 8; e++)
                    o8[e] = f2bf((bf2f(a8[e]) + bf2f(b8[e])) * binv[r / RPI]);
                *(short8*)&Bs[(r + rA) * BK + kA] = o8;
            }
        } else {
#pragma unroll
            for (int r = 0; r < BN; r += RPI)
                load_lds16(Bp + (size_t)(n0 + r + rA) * ldb + k0 + kAs,
                           &Bs[(r + rA) * BK + kA]);
        }
        __syncthreads();

#pragma unroll
        for (int ks = 0; ks < KS; ks++) {
            short8 af[MT], bfr[NT];
#pragma unroll
            for (int mt = 0; mt < MT; mt++)
                af[mt] = *(const short8*)&As[(wm + mt * 16 + lr) * BK + ((ks * 32 + lq * 8) ^ xorv)];
#pragma unroll
            for (int nt = 0; nt < NT; nt++)
                bfr[nt] = *(const short8*)&Bs[(wn + nt * 16 + lr) * BK + ((ks * 32 + lq * 8) ^ xorv)];
#pragma unroll
            for (int mt = 0; mt < MT; mt++)
#pragma unroll
                for (int nt = 0; nt < NT; nt++)
                    acc[mt][nt] = __builtin_amdgcn_mfma_f32_16x16x32_bf16(
                        af[mt], bfr[nt], acc[mt][nt], 0, 0, 0);
        }
        __syncthreads();
    }

    const size_t cz = (size_t)z * sC;
    if (MODE >= 1) {
        short* Cs = lds;
        char* Cs8 = (char*)lds;
        short* CoutS = (short*)Cv;
        char* Cout8 = (char*)Cv;
#pragma unroll
        for (int c = 0; c < BM / 64; c++) {
            if (wm == c * 64) {
#pragma unroll
                for (int mt = 0; mt < MT; mt++) {
#pragma unroll
                    for (int r = 0; r < 4; r++) {
                        const int rowLoc = wm + mt * 16 + lq * 4 + r;
                        const int rowCs = rowLoc - c * 64;
                        const float bm = BIAS_M ? bias[m0 + rowLoc] : 0.f;
#pragma unroll
                        for (int nt = 0; nt < NT; nt++) {
                            const int colLoc = wn + nt * 16 + lr;
                            float v = acc[mt][nt][r] * scale + bm;
                            if (BIAS_N) v += bias[n0 + colLoc];
                            if (FP8OUT) {
                                const int p = pk_fp8(v, 0.f);
                                Cs8[rowCs * CP8 + colLoc] = (char)(p & 0xff);
                            } else {
                                Cs[rowCs * CPITCH + colLoc] = f2bf(v);
                            }
                        }
                    }
                }
            }
            __syncthreads();
            if (FP8OUT) {
                constexpr int VPR = BN / 16;
                constexpr int ITER = 64 * VPR / 256;
#pragma unroll
                for (int i = 0; i < ITER; i++) {
                    const int idx = i * 256 + t;
                    const int row = idx / VPR;
                    const int cv = idx % VPR;
                    int4 val = *(const int4*)&Cs8[row * CP8 + cv * 16];
                    *(int4*)&Cout8[cz + (size_t)(m0 + c * 64 + row) * ldc + n0 + cv * 16] = val;
                }
            } else {
                constexpr int VPR = BN / 8;
                constexpr int ITER = 64 * VPR / 256;
#pragma unroll
                for (int i = 0; i < ITER; i++) {
                    const int idx = i * 256 + t;
                    const int row = idx / VPR;
                    const int cv = idx % VPR;
                    short8 val = *(const short8*)&Cs[row * CPITCH + cv * 8];
                    *(short8*)&CoutS[cz + (size_t)(m0 + c * 64 + row) * ldc + n0 + cv * 8] = val;
                }
            }
            if (c + 1 < BM / 64) __syncthreads();
        }
    } else {
#pragma unroll
        for (int mt = 0; mt < MT; mt++) {
#pragma unroll
            for (int r = 0; r < 4; r++) {
                const int row = m0 + wm + mt * 16 + lq * 4 + r;
                const float bm = BIAS_M ? bias[row] : 0.f;
#pragma unroll
                for (int nt = 0; nt < NT; nt++) {
                    const int col = n0 + wn + nt * 16 + lr;
                    float v = acc[mt][nt][r] * scale + bm;
                    if (BIAS_N) v += bias[col];
                    const size_t idx = cz + (size_t)row * ldc + col;
                    if (ADD_RES) v += res[idx];
                    ((float*)Cv)[idx] = v;
                }
            }
        }
    }
}

// ---------------------------------------------------------------------------
// Launch
// ---------------------------------------------------------------------------
extern "C" void kernel_launch(void* const* d_in, const int* in_sizes, int n_in,
                              void* d_out, int out_size, void* d_ws, size_t ws_size,
                              hipStream_t stream)
{
    (void)in_sizes; (void)n_in; (void)out_size; (void)ws_size;
    const float* x      = (const float*)d_in[0];
    const float* norm_w = (const float*)d_in[1];
    const float* norm_b = (const float*)d_in[2];
    const float* q_w    = (const float*)d_in[3];
    const float* q_b    = (const float*)d_in[4];
    const float* k_w    = (const float*)d_in[5];
    const float* k_b    = (const float*)d_in[6];
    const float* v_w    = (const float*)d_in[7];
    const float* v_b    = (const float*)d_in[8];
    const float* p_w    = (const float*)d_in[9];
    const float* p_b    = (const float*)d_in[10];

    const size_t CN2 = (size_t)NTOK * CH;

    short* hnT = (short*)d_ws;                        // [B][N][C] bf16
    short* QK  = hnT + (size_t)BATCH * CN2;           // [B][N][1024] bf16; later PV partials [2][B][N][C]
    short* V   = QK  + (size_t)BATCH * NTOK * 1024;   // region reused: V fp8 [B][C][N]
    short* O   = V   + (size_t)BATCH * CN2;           // (unused)
    short* wqk = O   + (size_t)BATCH * CN2;           // [1024][512] bf16
    short* wv  = wqk + (size_t)1024 * CH;
    short* wp  = wv  + (size_t)CH * CH;
    short* S   = wp  + (size_t)CH * CH;               // region reused: E fp8 [B][N][N]
    float* qkb = (float*)(S + (size_t)BATCH * NTOK * NTOK);   // [1024]
    float2* partials = (float2*)(qkb + 1024);                 // [512]
    float* RS = (float*)(partials + 512);                     // [B][N] rowsums

    char* V8 = (char*)V;
    char* S8 = (char*)S;

    gn_stats_partial<<<dim3(4, BATCH * NGRP), 256, 0, stream>>>(x, partials);
    cast_weights<<<dim3(256, 4), 256, 0, stream>>>(q_w, k_w, v_w, p_w, wqk, wv, wp);
    concat_bias<<<4, 256, 0, stream>>>(q_b, k_b, qkb);
    zero_f32<<<BATCH * NTOK / 256, 256, 0, stream>>>(RS);
    gn_apply_t<<<dim3(NTOK / 32, CH / 32, BATCH), 256, 0, stream>>>(
        x, norm_w, norm_b, partials, hnT);

    // Fused Q+K conv (128^2, BK=64), bf16 out
    mfma_gemm<128, 128, 64, 2, 1, 0, 1, 0, 0, 0, 0, 0, 0><<<dim3(1024 / 128, NTOK / 128, BATCH), 256, 0, stream>>>(
        hnT, wqk, nullptr, QK, qkb, nullptr, nullptr, 1.f, CH, CH, CH, 1024,
        (long)CN2, 0, (long)NTOK * 1024);
    // V conv -> fp8 V [C][N] (ldc/sC in BYTES)
    mfma_gemm<128, 128, 64, 2, 1, 1, 0, 0, 0, 0, 0, 0, 1><<<dim3(NTOK / 128, CH / 128, BATCH), 256, 0, stream>>>(
        wv, hnT, nullptr, V8, v_b, nullptr, nullptr, 1.f, CH, CH, CH, NTOK,
        0, (long)CN2, (long)CN2);

    const float scale = 1.0f / sqrtf((float)CH);
    // scores -> E = exp(s*scale) as FP8 e4m3 + fused fp32 row sums.
    // ldc/sC in BYTES for the fp8 output.
    gemm8p<2, 0, 0><<<dim3(NTOK / 256, NTOK / 256, BATCH), 512, 0, stream>>>(
        QK, QK + CH, S8, RS, scale, CH, 1024, 1024, NTOK,
        (long)NTOK * 1024, (long)NTOK * 1024, (long)NTOK * NTOK);
    // PV split-K=2, FP8 operands (E, V), 4-phase 256^2, bf16 partials out.
    // lda/ldb/sA/sB in BYTES (fp8); ldc/sC in shorts.
    gemm8p_fp8<1, 1><<<dim3(NTOK / 256, CH / 256, 8), 512, 0, stream>>>(
        S8, V8, QK, 1.f, NTOK / 2, NTOK, NTOK, CH,
        (long)NTOK * NTOK, (long)CN2, (long)CN2);

    // proj + bias + residual -> out fp32 [b][c][n].
    // B operand built in-staging: (P0 + P1) / RS.
    mfma_gemm<128, 128, 64, 2, 0, 1, 0, 1, 0, 0, 0, 1, 0><<<dim3(NTOK / 128, CH / 128, BATCH), 256, 0, stream>>>(
        wp, QK, QK + (size_t)BATCH * CN2, d_out, p_b, x, RS, 1.f,
        CH, CH, CH, NTOK, 0, (long)CN2, (long)CN2);
}

// Round 12
// 350.358 us; speedup vs baseline: 1.0095x; 1.0095x over previous
//
#include <hip/hip_runtime.h>
#include <math.h>

#define BATCH 4
#define CH 512
#define NTOK 4096
#define NGRP 32
#define CPG 16
#define GN_EPS 1e-6f

typedef __attribute__((ext_vector_type(8))) short short8;
typedef __attribute__((ext_vector_type(4))) short short4v;
typedef __attribute__((ext_vector_type(4))) float floatx4;

__device__ __forceinline__ short f2bf(float f) {
    unsigned u = __float_as_uint(f);
    u += 0x7fffu + ((u >> 16) & 1u);
    return (short)(u >> 16);
}
__device__ __forceinline__ float bf2f(short s) {
    return __uint_as_float(((unsigned)(unsigned short)s) << 16);
}
// pack 2 floats -> 2 fp8 e4m3 bytes (low 16 bits of result)
__device__ __forceinline__ int pk_fp8(float a, float b) {
    return __builtin_amdgcn_cvt_pk_fp8_f32(a, b, 0, false);
}

__device__ __forceinline__ void load_lds16(const void* g, void* l) {
    __builtin_amdgcn_global_load_lds(
        (const __attribute__((address_space(1))) void*)g,
        (__attribute__((address_space(3))) void*)l,
        16, 0, 0);
}

// ---------------------------------------------------------------------------
// GroupNorm stats, partial: grid (4 parts, 128 bg). partials[bg*4+p]=(sum,ssq)
// ---------------------------------------------------------------------------
__global__ __launch_bounds__(256)
void gn_stats_partial(const float* __restrict__ x, float2* __restrict__ partials)
{
    const int part = blockIdx.x;
    const int bg = blockIdx.y;
    const float4* xp = (const float4*)(x + (size_t)bg * CPG * NTOK) + part * 4096;
    float s = 0.f, ss = 0.f;
    for (int i = threadIdx.x; i < 4096; i += 256) {
        float4 v = xp[i];
        s  += v.x + v.y + v.z + v.w;
        ss += v.x * v.x + v.y * v.y + v.z * v.z + v.w * v.w;
    }
    __shared__ float r0[4], r1[4];
    for (int off = 32; off >= 1; off >>= 1) {
        s  += __shfl_down(s, off);
        ss += __shfl_down(ss, off);
    }
    const int lane = threadIdx.x & 63, wave = threadIdx.x >> 6;
    if (lane == 0) { r0[wave] = s; r1[wave] = ss; }
    __syncthreads();
    if (threadIdx.x == 0) {
        float2 o;
        o.x = r0[0] + r0[1] + r0[2] + r0[3];
        o.y = r1[0] + r1[1] + r1[2] + r1[3];
        partials[bg * 4 + part] = o;
    }
}

// ---------------------------------------------------------------------------
// GroupNorm apply + transpose + bf16. x[b][c][n] -> hnT[b][n][c] bf16.
// ---------------------------------------------------------------------------
__global__ __launch_bounds__(256)
void gn_apply_t(const float* __restrict__ x, const float* __restrict__ gamma,
                const float* __restrict__ beta, const float2* __restrict__ partials,
                short* __restrict__ hnT)
{
    const int b = blockIdx.z;
    const int c0 = blockIdx.y * 32;
    const int n0 = blockIdx.x * 32;
    __shared__ short tile[32][33];
    const int t = threadIdx.x;

    const int cl = t >> 3;
    const int nl = (t & 7) * 4;
    const int c = c0 + cl;
    const int bg = b * NGRP + c / CPG;
    float2 p0 = partials[bg * 4 + 0], p1 = partials[bg * 4 + 1];
    float2 p2 = partials[bg * 4 + 2], p3 = partials[bg * 4 + 3];
    const float inv = 1.f / (float)(CPG * NTOK);
    const float mean = (p0.x + p1.x + p2.x + p3.x) * inv;
    const float var = (p0.y + p1.y + p2.y + p3.y) * inv - mean * mean;
    const float rstd = rsqrtf(var + GN_EPS);
    const float ga = gamma[c] * rstd, be = beta[c] - mean * ga;
    const float4 v = *(const float4*)(x + ((size_t)b * CH + c) * NTOK + n0 + nl);
    tile[cl][nl + 0] = f2bf(v.x * ga + be);
    tile[cl][nl + 1] = f2bf(v.y * ga + be);
    tile[cl][nl + 2] = f2bf(v.z * ga + be);
    tile[cl][nl + 3] = f2bf(v.w * ga + be);
    __syncthreads();

    const int nw = t >> 3;
    const int cw = (t & 7) * 4;
    short4v o;
    o.x = tile[cw + 0][nw];
    o.y = tile[cw + 1][nw];
    o.z = tile[cw + 2][nw];
    o.w = tile[cw + 3][nw];
    *(short4v*)(hnT + ((size_t)b * NTOK + n0 + nw) * CH + c0 + cw) = o;
}

// ---------------------------------------------------------------------------
// Weight casts. Grid (256, 4).
// ---------------------------------------------------------------------------
__global__ __launch_bounds__(256)
void cast_weights(const float* q, const float* k, const float* v, const float* p,
                  short* wqk, short* wv, short* wp)
{
    const float* w; short* o;
    switch (blockIdx.y) {
        case 0: w = q; o = wqk; break;
        case 1: w = k; o = wqk + CH * CH; break;
        case 2: w = v; o = wv; break;
        default: w = p; o = wp; break;
    }
    const int i = blockIdx.x * 256 + threadIdx.x;
    const float4 vv = ((const float4*)w)[i];
    short4v s; s.x = f2bf(vv.x); s.y = f2bf(vv.y); s.z = f2bf(vv.z); s.w = f2bf(vv.w);
    ((short4v*)o)[i] = s;
}

__global__ __launch_bounds__(256)
void concat_bias(const float* q_b, const float* k_b, float* qkb)
{
    const int i = blockIdx.x * 256 + threadIdx.x;
    qkb[i] = (i < CH) ? q_b[i] : k_b[i - CH];
}

__global__ __launch_bounds__(256)
void zero_f32(float* __restrict__ p)
{
    p[blockIdx.x * 256 + threadIdx.x] = 0.f;
}

// ---------------------------------------------------------------------------
// 256x256 4-phase FP8 GEMM (TN), 512 threads, counted-vmcnt pipeline
// + T2 swizzle + T5 setprio. BK=128 fp8 elems = 128B rows: byte-identical
// memory geometry (staging, swizzle, vmcnt ledger) to the verified bf16
// BK=64 kernel. A,B fp8 e4m3; MFMA f32_16x16x32_fp8_fp8 (bf16 rate,
// half the bytes, 32 MFMA per barrier-pair).
// MODE 2 = fp8 exp(out) + fused fp32 row-sum atomics (scores).
// MODE 1 = bf16 out (PV split-K partials).
// ---------------------------------------------------------------------------
#define BAR8() asm volatile("s_barrier" ::: "memory")
#define WAITV4() asm volatile("s_waitcnt vmcnt(4)" ::: "memory")
#define WAITV0() asm volatile("s_waitcnt vmcnt(0)" ::: "memory")
#define LGKMW() asm volatile("s_waitcnt lgkmcnt(0)" ::: "memory")

#define STAGE_A8(bufp, kt, u) do {                                            \
    const int r0_ = arow0 + (u) * 64;                                         \
    load_lds16(Ap + (size_t)(m0 + r0_) * lda + (kt) * 128 + sc * 16,          \
               &ldsb[(bufp) * NSHB + r0_ * 128 + lc * 16]);                   \
    load_lds16(Ap + (size_t)(m0 + r0_ + 128) * lda + (kt) * 128 + sc * 16,    \
               &ldsb[(bufp) * NSHB + (r0_ + 128) * 128 + lc * 16]);           \
} while (0)

#define STAGE_B8(bufp, kt, u) do {                                            \
    const int r0_ = brow0 + (u) * 32;                                         \
    load_lds16(Bp + (size_t)(n0 + r0_) * ldb + (kt) * 128 + sc * 16,          \
               &ldsb[(bufp) * NSHB + 32768 + r0_ * 128 + lc * 16]);           \
    load_lds16(Bp + (size_t)(n0 + r0_ + 128) * ldb + (kt) * 128 + sc * 16,    \
               &ldsb[(bufp) * NSHB + 32768 + (r0_ + 128) * 128 + lc * 16]);   \
} while (0)

#define READA8(bufp, mh) do {                                                 \
    const char* bp_ = &ldsb[(bufp) * NSHB];                                   \
    _Pragma("unroll")                                                         \
    for (int mt = 0; mt < 4; mt++) {                                          \
        const int row_ = wr * 128 + (mh) * 64 + mt * 16 + lr;                 \
        _Pragma("unroll")                                                     \
        for (int ks = 0; ks < 4; ks++) {                                      \
            const int off = ks * 32 + lq * 8;                                 \
            const int swz = (((off >> 4) ^ (lr & 7)) << 4) | (off & 15);      \
            af8[mt][ks] = *(const long*)&bp_[row_ * 128 + swz];               \
        }                                                                     \
    } } while (0)

#define READB8(bufp, nh) do {                                                 \
    const char* bp_ = &ldsb[(bufp) * NSHB + 32768];                           \
    _Pragma("unroll")                                                         \
    for (int nt = 0; nt < 2; nt++) {                                          \
        const int row_ = wc * 64 + (nh) * 32 + nt * 16 + lr;                  \
        _Pragma("unroll")                                                     \
        for (int ks = 0; ks < 4; ks++) {                                      \
            const int off = ks * 32 + lq * 8;                                 \
            const int swz = (((off >> 4) ^ (lr & 7)) << 4) | (off & 15);      \
            bfr8[(nh) * 2 + nt][ks] = *(const long*)&bp_[row_ * 128 + swz];   \
        }                                                                     \
    } } while (0)

#define MMAQ8(mh, nh) do {                                                    \
    __builtin_amdgcn_s_setprio(1);                                            \
    _Pragma("unroll")                                                         \
    for (int mt = 0; mt < 4; mt++)                                            \
        _Pragma("unroll")                                                     \
        for (int nt = 0; nt < 2; nt++)                                        \
            _Pragma("unroll")                                                 \
            for (int ks = 0; ks < 4; ks++)                                    \
                acc[(mh)*4+mt][(nh)*2+nt] =                                   \
                    __builtin_amdgcn_mfma_f32_16x16x32_fp8_fp8(               \
                        af8[mt][ks], bfr8[(nh)*2+nt][ks],                     \
                        acc[(mh)*4+mt][(nh)*2+nt], 0, 0, 0);                  \
    __builtin_amdgcn_s_setprio(0);                                            \
} while (0)

template<int MODE, int SWAP_XY, int SPLITK>
__global__ __launch_bounds__(512)
void gemm8p_fp8(const char* __restrict__ A, const char* __restrict__ B,
                void* __restrict__ Cout, float* __restrict__ rs, float scale,
                int K, int lda, int ldb, int ldc, long sA, long sB, long sC)
{
    constexpr int NSHB = 65536;                 // bytes per K-tile buffer
    __shared__ __align__(16) char ldsb[131072];

    const int z = blockIdx.z;
    const int zb = SPLITK ? (z & 3) : z;
    const int koff = SPLITK ? (z >> 2) * K : 0;
    const char* Ap = A + (size_t)zb * sA + koff;
    const char* Bp = B + (size_t)zb * sB + koff;
    const int m0 = (SWAP_XY ? blockIdx.x : blockIdx.y) * 256;
    const int n0 = (SWAP_XY ? blockIdx.y : blockIdx.x) * 256;

    const int t = threadIdx.x;
    const int w = t >> 6, lane = t & 63;
    const int wr = w >> 2, wc = w & 3;
    const int lr = lane & 15, lq = lane >> 4;

    const int l8 = lane >> 3;
    const int lc = lane & 7;
    const int sc = lc ^ l8;              // T2 swizzled source chunk (16B)
    const int arow0 = w * 8 + l8;
    const int brow0 = (w >> 2) * 64 + (w & 3) * 8 + l8;

    long af8[4][4], bfr8[4][4];
    floatx4 acc[8][4];
#pragma unroll
    for (int i = 0; i < 8; i++)
#pragma unroll
        for (int j = 0; j < 4; j++)
            acc[i][j] = (floatx4){0.f, 0.f, 0.f, 0.f};

    const int NKT = K >> 7;              // 128-elem K-tiles
    const int NIT = K >> 8;

    STAGE_A8(0, 0, 0); STAGE_B8(0, 0, 0); STAGE_A8(0, 0, 1); STAGE_B8(0, 0, 1);
    STAGE_A8(1, 1, 0); STAGE_B8(1, 1, 0);

    for (int it = 0; it < NIT; it++) {
        const int ktb = 2 * it + 1;
        int kt2 = 2 * it + 2; if (kt2 >= NKT) kt2 -= 2;
        int kt3 = 2 * it + 3; if (kt3 >= NKT) kt3 -= 2;
        // P0
        WAITV4(); BAR8();
        READA8(0, 0); READB8(0, 0); READB8(0, 1);
        STAGE_B8(1, ktb, 1); STAGE_A8(1, ktb, 1);
        BAR8(); LGKMW(); MMAQ8(0, 0); MMAQ8(0, 1); BAR8();
        // P1
        READA8(0, 1);
        STAGE_A8(0, kt2, 0); STAGE_B8(0, kt2, 0);
        BAR8(); LGKMW(); MMAQ8(1, 0); MMAQ8(1, 1); BAR8();
        // P2
        WAITV4(); BAR8();
        READA8(1, 0); READB8(1, 0); READB8(1, 1);
        STAGE_A8(0, kt2, 1); STAGE_B8(0, kt2, 1);
        BAR8(); LGKMW(); MMAQ8(0, 0); MMAQ8(0, 1); BAR8();
        // P3
        READA8(1, 1);
        STAGE_A8(1, kt3, 0); STAGE_B8(1, kt3, 0);
        BAR8(); LGKMW(); MMAQ8(1, 0); MMAQ8(1, 1); BAR8();
    }
    WAITV0(); BAR8();      // drain clamped tail stages before LDS reuse

    const size_t cz = (size_t)z * sC;
    if (MODE == 2) {
        // FP8 epilogue: E = exp(v) as e4m3 bytes; RS from fp32 pre-rounding.
        char* Cs8 = ldsb;                    // 256x256 bytes, chunk-swizzled
        char* Cout8 = (char*)Cout;
#pragma unroll
        for (int mh = 0; mh < 2; mh++)
#pragma unroll
            for (int mt = 0; mt < 4; mt++)
#pragma unroll
                for (int r = 0; r < 4; r++) {
                    const int row = wr * 128 + mh * 64 + mt * 16 + lq * 4 + r;
                    float v[4];
                    float sm = 0.f;
#pragma unroll
                    for (int nh = 0; nh < 2; nh++)
#pragma unroll
                        for (int nt = 0; nt < 2; nt++) {
                            float e = __expf(
                                acc[mh * 4 + mt][nh * 2 + nt][r] * scale);
                            v[nh * 2 + nt] = e;
                            sm += e;
                        }
                    const int rsw = row & 7;
                    const int base = row * 256;
                    const int p01 = pk_fp8(v[0], v[1]);
                    const int p23 = pk_fp8(v[2], v[3]);
                    Cs8[base + (((wc * 4 + 0) ^ rsw) << 4) + lr] = (char)(p01 & 0xff);
                    Cs8[base + (((wc * 4 + 1) ^ rsw) << 4) + lr] = (char)((p01 >> 8) & 0xff);
                    Cs8[base + (((wc * 4 + 2) ^ rsw) << 4) + lr] = (char)(p23 & 0xff);
                    Cs8[base + (((wc * 4 + 3) ^ rsw) << 4) + lr] = (char)((p23 >> 8) & 0xff);
                    sm += __shfl_xor(sm, 1);
                    sm += __shfl_xor(sm, 2);
                    sm += __shfl_xor(sm, 4);
                    sm += __shfl_xor(sm, 8);
                    if (lr == 0)
                        atomicAdd(&rs[(size_t)zb * NTOK + m0 + row], sm);
                }
        __syncthreads();
#pragma unroll
        for (int i2 = 0; i2 < 8; i2++) {
            const int idx = i2 * 512 + t;          // 4096 16B-chunks
            const int row = idx >> 4;
            const int ch = idx & 15;
            int4 val = *(const int4*)&Cs8[row * 256 + ((ch ^ (row & 7)) << 4)];
            *(int4*)&Cout8[cz + (size_t)(m0 + row) * ldc + n0 + ch * 16] = val;
        }
    } else {
        // bf16 epilogue (row-XOR-swizzled Cs + coalesced 512B stores)
        short* Cs = (short*)ldsb;
        short* CoutS = (short*)Cout;
#pragma unroll
        for (int mh = 0; mh < 2; mh++)
#pragma unroll
            for (int mt = 0; mt < 4; mt++)
#pragma unroll
                for (int r = 0; r < 4; r++) {
                    const int row = wr * 128 + mh * 64 + mt * 16 + lq * 4 + r;
#pragma unroll
                    for (int nh = 0; nh < 2; nh++)
#pragma unroll
                        for (int nt = 0; nt < 2; nt++) {
                            const int col = wc * 64 + nh * 32 + nt * 16 + lr;
                            float v = acc[mh * 4 + mt][nh * 2 + nt][r] * scale;
                            Cs[row * 256 + (col ^ ((row & 7) << 4))] = f2bf(v);
                        }
                }
        __syncthreads();
#pragma unroll
        for (int i2 = 0; i2 < 16; i2++) {
            const int row = w * 32 + i2 * 2 + (lane >> 5);
            const int col = (lane & 31) * 8;
            short8 val = *(const short8*)&Cs[row * 256 + (col ^ ((row & 7) << 4))];
            *(short8*)&CoutS[cz + (size_t)(m0 + row) * ldc + n0 + col] = val;
        }
    }
}

// ---------------------------------------------------------------------------
// bf16 MFMA GEMM (TN) 128x128 2-barrier. T2 swizzle.
// FP8OUT (MODE 1): epilogue converts to fp8 e4m3 (QK conv, V conv).
// B_COMBINE: B operand is (B + B2)/rs[row] built in reg-staging (proj).
// ---------------------------------------------------------------------------
template<int BM, int BN, int BK, int WAVES_M, int MODE, int BIAS_M,
         int BIAS_N, int ADD_RES, int SWAP_XY, int SPLITK, int RSUM,
         int B_COMBINE, int FP8OUT>
__global__ __launch_bounds__(256)
void mfma_gemm(const short* __restrict__ A, const short* __restrict__ B,
               const short* __restrict__ B2, void* __restrict__ Cv,
               const float* __restrict__ bias, const float* __restrict__ res,
               float* __restrict__ rs, float scale,
               int K, int lda, int ldb, int ldc,
               long sA, long sB, long sC)
{
    constexpr int WAVES_N = 4 / WAVES_M;
    constexpr int WM = BM / WAVES_M;
    constexpr int WN = BN / WAVES_N;
    constexpr int MT = WM / 16;
    constexpr int NT = WN / 16;
    constexpr int KS = BK / 32;
    constexpr int TPR = BK / 8;
    constexpr int RPI = 256 / TPR;
    constexpr int CPITCH = BN + 8;
    constexpr int CP8 = BN + 32;
    constexpr int STAGE = BM * BK + BN * BK;
    constexpr int EPI = (MODE >= 1) ? (FP8OUT ? (64 * CP8 + 1) / 2 : 64 * CPITCH) : 0;
    constexpr int LDSE = STAGE > EPI ? STAGE : EPI;

    __shared__ __align__(16) short lds[LDSE];
    short* As = lds;
    short* Bs = lds + BM * BK;

    const int z = blockIdx.z;
    const int zb = SPLITK ? (z & 3) : z;
    const int koff = SPLITK ? (z >> 2) * K : 0;
    const short* Ap = A + (size_t)zb * sA + koff;
    const short* Bp = B + (size_t)zb * sB + koff;
    const short* Bp2 = B_COMBINE ? (B2 + (size_t)zb * sB + koff) : nullptr;

    const int m0 = (SWAP_XY ? blockIdx.x : blockIdx.y) * BM;
    const int n0 = (SWAP_XY ? blockIdx.y : blockIdx.x) * BN;
    const int t = threadIdx.x;
    const int w = t >> 6, lane = t & 63;
    const int wm = (w % WAVES_M) * WM;
    const int wn = (w / WAVES_M) * WN;
    const int lr = lane & 15, lq = lane >> 4;

    floatx4 acc[MT][NT];
#pragma unroll
    for (int mt = 0; mt < MT; mt++)
#pragma unroll
        for (int nt = 0; nt < NT; nt++)
            acc[mt][nt] = (floatx4){0.f, 0.f, 0.f, 0.f};

    const int rA = t / TPR;
    const int kA = (t % TPR) * 8;
    const int kAs = ((t % TPR) ^ (rA & (TPR - 1))) * 8;
    const int xorv = (lr & (TPR - 1)) * 8;

    float binv[B_COMBINE ? BN / RPI : 1];
    if (B_COMBINE) {
#pragma unroll
        for (int r = 0; r < BN / RPI; r++)
            binv[r] = 1.f / rs[(size_t)zb * NTOK + n0 + r * RPI + rA];
    }

    for (int k0 = 0; k0 < K; k0 += BK) {
#pragma unroll
        for (int r = 0; r < BM; r += RPI)
            load_lds16(Ap + (size_t)(m0 + r + rA) * lda + k0 + kAs,
                       &As[(r + rA) * BK + kA]);
        if (B_COMBINE) {
#pragma unroll
            for (int r = 0; r < BN; r += RPI) {
                const size_t off = (size_t)(n0 + r + rA) * ldb + k0 + kAs;
                short8 a8 = *(const short8*)&Bp[off];
                short8 b8 = *(const short8*)&Bp2[off];
                short8 o8;
#pragma unroll
                for (int e = 0; e < 8; e++)
                    o8[e] = f2bf((bf2f(a8[e]) + bf2f(b8[e])) * binv[r / RPI]);
                *(short8*)&Bs[(r + rA) * BK + kA] = o8;
            }
        } else {
#pragma unroll
            for (int r = 0; r < BN; r += RPI)
                load_lds16(Bp + (size_t)(n0 + r + rA) * ldb + k0 + kAs,
                           &Bs[(r + rA) * BK + kA]);
        }
        __syncthreads();

#pragma unroll
        for (int ks = 0; ks < KS; ks++) {
            short8 af[MT], bfr[NT];
#pragma unroll
            for (int mt = 0; mt < MT; mt++)
                af[mt] = *(const short8*)&As[(wm + mt * 16 + lr) * BK + ((ks * 32 + lq * 8) ^ xorv)];
#pragma unroll
            for (int nt = 0; nt < NT; nt++)
                bfr[nt] = *(const short8*)&Bs[(wn + nt * 16 + lr) * BK + ((ks * 32 + lq * 8) ^ xorv)];
#pragma unroll
            for (int mt = 0; mt < MT; mt++)
#pragma unroll
                for (int nt = 0; nt < NT; nt++)
                    acc[mt][nt] = __builtin_amdgcn_mfma_f32_16x16x32_bf16(
                        af[mt], bfr[nt], acc[mt][nt], 0, 0, 0);
        }
        __syncthreads();
    }

    const size_t cz = (size_t)z * sC;
    if (MODE >= 1) {
        short* Cs = lds;
        char* Cs8 = (char*)lds;
        short* CoutS = (short*)Cv;
        char* Cout8 = (char*)Cv;
#pragma unroll
        for (int c = 0; c < BM / 64; c++) {
            if (wm == c * 64) {
#pragma unroll
                for (int mt = 0; mt < MT; mt++) {
#pragma unroll
                    for (int r = 0; r < 4; r++) {
                        const int rowLoc = wm + mt * 16 + lq * 4 + r;
                        const int rowCs = rowLoc - c * 64;
                        const float bm = BIAS_M ? bias[m0 + rowLoc] : 0.f;
#pragma unroll
                        for (int nt = 0; nt < NT; nt++) {
                            const int colLoc = wn + nt * 16 + lr;
                            float v = acc[mt][nt][r] * scale + bm;
                            if (BIAS_N) v += bias[n0 + colLoc];
                            if (FP8OUT) {
                                const int p = pk_fp8(v, 0.f);
                                Cs8[rowCs * CP8 + colLoc] = (char)(p & 0xff);
                            } else {
                                Cs[rowCs * CPITCH + colLoc] = f2bf(v);
                            }
                        }
                    }
                }
            }
            __syncthreads();
            if (FP8OUT) {
                constexpr int VPR = BN / 16;
                constexpr int ITER = 64 * VPR / 256;
#pragma unroll
                for (int i = 0; i < ITER; i++) {
                    const int idx = i * 256 + t;
                    const int row = idx / VPR;
                    const int cv = idx % VPR;
                    int4 val = *(const int4*)&Cs8[row * CP8 + cv * 16];
                    *(int4*)&Cout8[cz + (size_t)(m0 + c * 64 + row) * ldc + n0 + cv * 16] = val;
                }
            } else {
                constexpr int VPR = BN / 8;
                constexpr int ITER = 64 * VPR / 256;
#pragma unroll
                for (int i = 0; i < ITER; i++) {
                    const int idx = i * 256 + t;
                    const int row = idx / VPR;
                    const int cv = idx % VPR;
                    short8 val = *(const short8*)&Cs[row * CPITCH + cv * 8];
                    *(short8*)&CoutS[cz + (size_t)(m0 + c * 64 + row) * ldc + n0 + cv * 8] = val;
                }
            }
            if (c + 1 < BM / 64) __syncthreads();
        }
    } else {
#pragma unroll
        for (int mt = 0; mt < MT; mt++) {
#pragma unroll
            for (int r = 0; r < 4; r++) {
                const int row = m0 + wm + mt * 16 + lq * 4 + r;
                const float bm = BIAS_M ? bias[row] : 0.f;
#pragma unroll
                for (int nt = 0; nt < NT; nt++) {
                    const int col = n0 + wn + nt * 16 + lr;
                    float v = acc[mt][nt][r] * scale + bm;
                    if (BIAS_N) v += bias[col];
                    const size_t idx = cz + (size_t)row * ldc + col;
                    if (ADD_RES) v += res[idx];
                    ((float*)Cv)[idx] = v;
                }
            }
        }
    }
}

// ---------------------------------------------------------------------------
// Launch
// ---------------------------------------------------------------------------
extern "C" void kernel_launch(void* const* d_in, const int* in_sizes, int n_in,
                              void* d_out, int out_size, void* d_ws, size_t ws_size,
                              hipStream_t stream)
{
    (void)in_sizes; (void)n_in; (void)out_size; (void)ws_size;
    const float* x      = (const float*)d_in[0];
    const float* norm_w = (const float*)d_in[1];
    const float* norm_b = (const float*)d_in[2];
    const float* q_w    = (const float*)d_in[3];
    const float* q_b    = (const float*)d_in[4];
    const float* k_w    = (const float*)d_in[5];
    const float* k_b    = (const float*)d_in[6];
    const float* v_w    = (const float*)d_in[7];
    const float* v_b    = (const float*)d_in[8];
    const float* p_w    = (const float*)d_in[9];
    const float* p_b    = (const float*)d_in[10];

    const size_t CN2 = (size_t)NTOK * CH;

    short* hnT = (short*)d_ws;                        // [B][N][C] bf16
    short* QK  = hnT + (size_t)BATCH * CN2;           // fp8 QK [B][N][1024]; later PV partials [2][B][N][C] bf16
    short* V   = QK  + (size_t)BATCH * NTOK * 1024;   // fp8 V [B][C][N]
    short* O   = V   + (size_t)BATCH * CN2;           // (unused)
    short* wqk = O   + (size_t)BATCH * CN2;           // [1024][512] bf16
    short* wv  = wqk + (size_t)1024 * CH;
    short* wp  = wv  + (size_t)CH * CH;
    short* S   = wp  + (size_t)CH * CH;               // fp8 E [B][N][N]
    float* qkb = (float*)(S + (size_t)BATCH * NTOK * NTOK);   // [1024]
    float2* partials = (float2*)(qkb + 1024);                 // [512]
    float* RS = (float*)(partials + 512);                     // [B][N] rowsums

    char* QK8 = (char*)QK;
    char* V8 = (char*)V;
    char* S8 = (char*)S;

    gn_stats_partial<<<dim3(4, BATCH * NGRP), 256, 0, stream>>>(x, partials);
    cast_weights<<<dim3(256, 4), 256, 0, stream>>>(q_w, k_w, v_w, p_w, wqk, wv, wp);
    concat_bias<<<4, 256, 0, stream>>>(q_b, k_b, qkb);
    zero_f32<<<BATCH * NTOK / 256, 256, 0, stream>>>(RS);
    gn_apply_t<<<dim3(NTOK / 32, CH / 32, BATCH), 256, 0, stream>>>(
        x, norm_w, norm_b, partials, hnT);

    // Fused Q+K conv -> fp8 QK [N][1024] (ldc/sC in BYTES)
    mfma_gemm<128, 128, 64, 2, 1, 0, 1, 0, 0, 0, 0, 0, 1><<<dim3(1024 / 128, NTOK / 128, BATCH), 256, 0, stream>>>(
        hnT, wqk, nullptr, QK8, qkb, nullptr, nullptr, 1.f, CH, CH, CH, 1024,
        (long)CN2, 0, (long)NTOK * 1024);
    // V conv -> fp8 V [C][N] (ldc/sC in BYTES)
    mfma_gemm<128, 128, 64, 2, 1, 1, 0, 0, 0, 0, 0, 0, 1><<<dim3(NTOK / 128, CH / 128, BATCH), 256, 0, stream>>>(
        wv, hnT, nullptr, V8, v_b, nullptr, nullptr, 1.f, CH, CH, CH, NTOK,
        0, (long)CN2, (long)CN2);

    const float scale = 1.0f / sqrtf((float)CH);
    // scores: fp8 Q x fp8 K -> E = exp(s*scale) fp8 + fused fp32 row sums.
    // A = Q bytes [n][0..512), B = K bytes [n][512..1024). All strides BYTES.
    gemm8p_fp8<2, 0, 0><<<dim3(NTOK / 256, NTOK / 256, BATCH), 512, 0, stream>>>(
        QK8, QK8 + 512, S8, RS, scale, CH, 1024, 1024, NTOK,
        (long)NTOK * 1024, (long)NTOK * 1024, (long)NTOK * NTOK);
    // PV split-K=2, fp8 operands (E, V), bf16 partials -> QK region.
    // lda/ldb/sA/sB in BYTES; ldc/sC in shorts.
    gemm8p_fp8<1, 1, 1><<<dim3(NTOK / 256, CH / 256, 8), 512, 0, stream>>>(
        S8, V8, QK, nullptr, 1.f, NTOK / 2, NTOK, NTOK, CH,
        (long)NTOK * NTOK, (long)CN2, (long)CN2);

    // proj + bias + residual -> out fp32 [b][c][n].
    // B operand built in-staging: (P0 + P1) / RS.
    mfma_gemm<128, 128, 64, 2, 0, 1, 0, 1, 0, 0, 0, 1, 0><<<dim3(NTOK / 128, CH / 128, BATCH), 256, 0, stream>>>(
        wp, QK, QK + (size_t)BATCH * CN2, d_out, p_b, x, RS, 1.f,
        CH, CH, CH, NTOK, 0, (long)CN2, (long)CN2);
}